// Round 3
// baseline (151.677 us; speedup 1.0000x reference)
//
#include <hip/hip_runtime.h>

// Keep IEEE mul-then-add semantics (match JAX/XLA fp32 reference; near-tie
// d0<d1 coset decisions are sensitive to contraction).
#pragma clang fp contract(off)

#define TINY_EPS 1.1920928955078125e-07f  // np.finfo(float32).eps

// Native clang vector type: __builtin_nontemporal_* requires a real vector,
// not HIP's float4 class.
typedef float f4 __attribute__((ext_vector_type(4)));

// D8 closest point, replicating the reference's branchy logic exactly.
// All array indexing is compile-time constant after unrolling (no scratch).
__device__ __forceinline__ void dn8(const float z[8], float out[8]) {
    float f[8], delta[8];
    int par = 0;
#pragma unroll
    for (int j = 0; j < 8; ++j) {
        float x  = z[j];
        float sg = (x > 0.0f) ? 1.0f : ((x < 0.0f) ? -1.0f : 0.0f);
        float fv = floorf((x - sg * TINY_EPS) + 0.5f);  // custom_round
        f[j]     = fv;
        delta[j] = fabsf(x - fv);
        par += (int)fv;  // exact: fv is a small integer-valued float
    }
    // first-max argmax; carry z[k], f[k] along so no runtime indexing
    int   k  = 0;
    float bd = delta[0], xk = z[0], fk = f[0];
#pragma unroll
    for (int j = 1; j < 8; ++j) {
        bool better = delta[j] > bd;  // strict: first max wins (jnp.argmax)
        bd = better ? delta[j] : bd;
        xk = better ? z[j] : xk;
        fk = better ? f[j] : fk;
        k  = better ? j : k;
    }
    // flip direction: x>=0 ? (f<x) : (f<=x)
    bool  up  = (xk >= 0.0f) ? (fk < xk) : (fk <= xk);
    float adj = fk + (up ? 1.0f : -1.0f);
    bool  odd = (par & 1) != 0;
#pragma unroll
    for (int j = 0; j < 8; ++j)
        out[j] = (odd && (j == k)) ? adj : f[j];
}

// One E8 point: z[8] -> q[8] (scaled by beta).
__device__ __forceinline__ void e8_point(const float z[8], float beta, float q[8]) {
    // coset 0: D8(z)
    float y0[8];
    dn8(z, y0);

    // coset 1: D8(z - 0.5) + 0.5
    float zs[8], y1[8];
#pragma unroll
    for (int j = 0; j < 8; ++j) zs[j] = z[j] - 0.5f;
    dn8(zs, y1);
#pragma unroll
    for (int j = 0; j < 8; ++j) y1[j] = y1[j] + 0.5f;

    // squared distances, sequential order j=0..7, explicit round-to-nearest
    // ops (immune to contraction) to bit-match the reference's mul-then-sum.
    float d0 = 0.0f, d1 = 0.0f;
#pragma unroll
    for (int j = 0; j < 8; ++j) {
        float t0 = __fsub_rn(z[j], y0[j]);
        d0       = __fadd_rn(d0, __fmul_rn(t0, t0));
        float t1 = __fsub_rn(z[j], y1[j]);
        d1       = __fadd_rn(d1, __fmul_rn(t1, t1));
    }
    bool pick0 = d0 < d1;  // ties -> y1, matching jnp.where(d0 < d1, y0, y1)

#pragma unroll
    for (int j = 0; j < 8; ++j) q[j] = beta * (pick0 ? y0[j] : y1[j]);
}

// 2 points per thread: 4 float4 loads issued up front (more MLP per wave),
// long ALU section, 4 float4 stores. Nontemporal: pure streaming, no reuse.
__global__ void __launch_bounds__(256)
e8_quant_kernel(const float* __restrict__ x, const float* __restrict__ beta_p,
                const float* __restrict__ eps, float* __restrict__ out, int N) {
    int i = blockIdx.x * blockDim.x + threadIdx.x;  // pair index
    int p0 = i * 2;
    if (p0 >= N) return;
    bool has2 = (p0 + 1) < N;

    float beta = *beta_p;
    float e[8];
#pragma unroll
    for (int j = 0; j < 8; ++j) e[j] = eps[j];  // uniform -> scalar loads

    const f4* xp = reinterpret_cast<const f4*>(x) + (size_t)p0 * 2;
    f4 a0 = __builtin_nontemporal_load(xp + 0);
    f4 a1 = __builtin_nontemporal_load(xp + 1);
    f4 b0 = {}, b1 = {};
    if (has2) {
        b0 = __builtin_nontemporal_load(xp + 2);
        b1 = __builtin_nontemporal_load(xp + 3);
    }

    float zA[8] = {a0.x, a0.y, a0.z, a0.w, a1.x, a1.y, a1.z, a1.w};
#pragma unroll
    for (int j = 0; j < 8; ++j) zA[j] = zA[j] / beta + e[j];  // IEEE div
    float qA[8];
    e8_point(zA, beta, qA);

    f4* op = reinterpret_cast<f4*>(out) + (size_t)p0 * 2;
    f4 sA0 = {qA[0], qA[1], qA[2], qA[3]};
    f4 sA1 = {qA[4], qA[5], qA[6], qA[7]};
    __builtin_nontemporal_store(sA0, op + 0);
    __builtin_nontemporal_store(sA1, op + 1);

    if (has2) {
        float zB[8] = {b0.x, b0.y, b0.z, b0.w, b1.x, b1.y, b1.z, b1.w};
#pragma unroll
        for (int j = 0; j < 8; ++j) zB[j] = zB[j] / beta + e[j];
        float qB[8];
        e8_point(zB, beta, qB);
        f4 sB0 = {qB[0], qB[1], qB[2], qB[3]};
        f4 sB1 = {qB[4], qB[5], qB[6], qB[7]};
        __builtin_nontemporal_store(sB0, op + 2);
        __builtin_nontemporal_store(sB1, op + 3);
    }
}

extern "C" void kernel_launch(void* const* d_in, const int* in_sizes, int n_in,
                              void* d_out, int out_size, void* d_ws, size_t ws_size,
                              hipStream_t stream) {
    const float* x      = (const float*)d_in[0];
    const float* beta_p = (const float*)d_in[1];
    const float* eps    = (const float*)d_in[2];
    float*       out    = (float*)d_out;

    int N      = in_sizes[0] / 8;        // 4,000,000 points
    int pairs  = (N + 1) / 2;            // 2 points per thread
    int block  = 256;
    int grid   = (pairs + block - 1) / block;
    hipLaunchKernelGGL(e8_quant_kernel, dim3(grid), dim3(block), 0, stream,
                       x, beta_p, eps, out, N);
}

// Round 4
// 49.270 us; speedup vs baseline: 3.0785x; 3.0785x over previous
//
#include <hip/hip_runtime.h>

// Keep IEEE mul-then-add semantics (match JAX/XLA fp32 reference; near-tie
// d0<d1 coset decisions are sensitive to contraction).
#pragma clang fp contract(off)

#define TINY_EPS 1.1920928955078125e-07f  // np.finfo(float32).eps

typedef float f4 __attribute__((ext_vector_type(4)));

// D8 closest point, replicating the reference's branchy logic exactly.
// All array indexing is compile-time constant after unrolling (no scratch).
__device__ __forceinline__ void dn8(const float z[8], float out[8]) {
    float f[8], delta[8];
    int par = 0;
#pragma unroll
    for (int j = 0; j < 8; ++j) {
        float x  = z[j];
        float sg = (x > 0.0f) ? 1.0f : ((x < 0.0f) ? -1.0f : 0.0f);
        float fv = floorf((x - sg * TINY_EPS) + 0.5f);  // custom_round
        f[j]     = fv;
        delta[j] = fabsf(x - fv);
        par += (int)fv;  // exact: fv is a small integer-valued float
    }
    // first-max argmax; carry z[k], f[k] along so no runtime indexing
    int   k  = 0;
    float bd = delta[0], xk = z[0], fk = f[0];
#pragma unroll
    for (int j = 1; j < 8; ++j) {
        bool better = delta[j] > bd;  // strict: first max wins (jnp.argmax)
        bd = better ? delta[j] : bd;
        xk = better ? z[j] : xk;
        fk = better ? f[j] : fk;
        k  = better ? j : k;
    }
    // flip direction: x>=0 ? (f<x) : (f<=x)
    bool  up  = (xk >= 0.0f) ? (fk < xk) : (fk <= xk);
    float adj = fk + (up ? 1.0f : -1.0f);
    bool  odd = (par & 1) != 0;
#pragma unroll
    for (int j = 0; j < 8; ++j)
        out[j] = (odd && (j == k)) ? adj : f[j];
}

// One E8 point: z[8] -> q[8] (scaled by beta).
__device__ __forceinline__ void e8_point(const float z[8], float beta, float q[8]) {
    float y0[8];
    dn8(z, y0);

    float zs[8], y1[8];
#pragma unroll
    for (int j = 0; j < 8; ++j) zs[j] = z[j] - 0.5f;
    dn8(zs, y1);
#pragma unroll
    for (int j = 0; j < 8; ++j) y1[j] = y1[j] + 0.5f;

    // squared distances, sequential order j=0..7, explicit round-to-nearest
    // ops (immune to contraction) to bit-match the reference's mul-then-sum.
    float d0 = 0.0f, d1 = 0.0f;
#pragma unroll
    for (int j = 0; j < 8; ++j) {
        float t0 = __fsub_rn(z[j], y0[j]);
        d0       = __fadd_rn(d0, __fmul_rn(t0, t0));
        float t1 = __fsub_rn(z[j], y1[j]);
        d1       = __fadd_rn(d1, __fmul_rn(t1, t1));
    }
    bool pick0 = d0 < d1;  // ties -> y1, matching jnp.where(d0 < d1, y0, y1)

#pragma unroll
    for (int j = 0; j < 8; ++j) q[j] = beta * (pick0 ? y0[j] : y1[j]);
}

// 2 points per thread: 4 float4 loads issued up front (2x MLP per wave),
// long ALU section, 4 float4 stores. Regular cached loads/stores: L2 merges
// the 16B/lane stores into full lines (nt broke this -> 1.6x write amp).
__global__ void __launch_bounds__(256)
e8_quant_kernel(const float* __restrict__ x, const float* __restrict__ beta_p,
                const float* __restrict__ eps, float* __restrict__ out, int N) {
    int i = blockIdx.x * blockDim.x + threadIdx.x;  // pair index
    int p0 = i * 2;
    if (p0 >= N) return;
    bool has2 = (p0 + 1) < N;

    float beta = *beta_p;
    float e[8];
#pragma unroll
    for (int j = 0; j < 8; ++j) e[j] = eps[j];  // uniform -> scalar loads

    const f4* xp = reinterpret_cast<const f4*>(x) + (size_t)p0 * 2;
    f4 a0 = xp[0];
    f4 a1 = xp[1];
    f4 b0 = {}, b1 = {};
    if (has2) {
        b0 = xp[2];
        b1 = xp[3];
    }

    float zA[8] = {a0.x, a0.y, a0.z, a0.w, a1.x, a1.y, a1.z, a1.w};
#pragma unroll
    for (int j = 0; j < 8; ++j) zA[j] = zA[j] / beta + e[j];  // IEEE div
    float qA[8];
    e8_point(zA, beta, qA);

    f4* op = reinterpret_cast<f4*>(out) + (size_t)p0 * 2;
    f4 sA0 = {qA[0], qA[1], qA[2], qA[3]};
    f4 sA1 = {qA[4], qA[5], qA[6], qA[7]};
    op[0] = sA0;
    op[1] = sA1;

    if (has2) {
        float zB[8] = {b0.x, b0.y, b0.z, b0.w, b1.x, b1.y, b1.z, b1.w};
#pragma unroll
        for (int j = 0; j < 8; ++j) zB[j] = zB[j] / beta + e[j];
        float qB[8];
        e8_point(zB, beta, qB);
        f4 sB0 = {qB[0], qB[1], qB[2], qB[3]};
        f4 sB1 = {qB[4], qB[5], qB[6], qB[7]};
        op[2] = sB0;
        op[3] = sB1;
    }
}

extern "C" void kernel_launch(void* const* d_in, const int* in_sizes, int n_in,
                              void* d_out, int out_size, void* d_ws, size_t ws_size,
                              hipStream_t stream) {
    const float* x      = (const float*)d_in[0];
    const float* beta_p = (const float*)d_in[1];
    const float* eps    = (const float*)d_in[2];
    float*       out    = (float*)d_out;

    int N      = in_sizes[0] / 8;        // 4,000,000 points
    int pairs  = (N + 1) / 2;            // 2 points per thread
    int block  = 256;
    int grid   = (pairs + block - 1) / block;
    hipLaunchKernelGGL(e8_quant_kernel, dim3(grid), dim3(block), 0, stream,
                       x, beta_p, eps, out, N);
}

// Round 5
// 42.857 us; speedup vs baseline: 3.5392x; 1.1497x over previous
//
#include <hip/hip_runtime.h>

// Keep IEEE mul-then-add semantics (match JAX/XLA fp32 reference; near-tie
// d0<d1 coset decisions are sensitive to contraction).
#pragma clang fp contract(off)

#define TINY_EPS 1.1920928955078125e-07f  // np.finfo(float32).eps

typedef float f4 __attribute__((ext_vector_type(4)));

// D8 closest point, replicating the reference's branchy logic exactly.
// custom_round: floor(x - sign(x)*eps + 0.5). copysign(eps,x) == sign(x)*eps
// exactly for x!=0; for x==+-0 both variants floor(0.5 -+ eps) = floor(0.5)=0.
// All array indexing is compile-time constant after unrolling (no scratch).
__device__ __forceinline__ void dn8(const float z[8], float out[8]) {
    float f[8], delta[8];
    int par = 0;
#pragma unroll
    for (int j = 0; j < 8; ++j) {
        float x  = z[j];
        float t  = x - __builtin_copysignf(TINY_EPS, x);  // 1 bfi + 1 sub
        float fv = floorf(t + 0.5f);
        f[j]     = fv;
        delta[j] = fabsf(x - fv);
        par += (int)fv;  // exact: fv is a small integer-valued float
    }
    // first-max argmax; carry z[k], f[k] along so no runtime indexing
    int   k  = 0;
    float bd = delta[0], xk = z[0], fk = f[0];
#pragma unroll
    for (int j = 1; j < 8; ++j) {
        bool better = delta[j] > bd;  // strict: first max wins (jnp.argmax)
        bd = better ? delta[j] : bd;
        xk = better ? z[j] : xk;
        fk = better ? f[j] : fk;
        k  = better ? j : k;
    }
    // flip direction: x>=0 ? (f<x) : (f<=x)
    bool  up  = (xk >= 0.0f) ? (fk < xk) : (fk <= xk);
    float adj = fk + (up ? 1.0f : -1.0f);
    bool  odd = (par & 1) != 0;
#pragma unroll
    for (int j = 0; j < 8; ++j)
        out[j] = (odd && (j == k)) ? adj : f[j];
}

// One E8 point: z[8] -> q[8] (scaled by beta).
__device__ __forceinline__ void e8_point(const float z[8], float beta, float q[8]) {
    float y0[8];
    dn8(z, y0);

    float zs[8], y1[8];
#pragma unroll
    for (int j = 0; j < 8; ++j) zs[j] = z[j] - 0.5f;
    dn8(zs, y1);
#pragma unroll
    for (int j = 0; j < 8; ++j) y1[j] = y1[j] + 0.5f;

    // squared distances, sequential order j=0..7, explicit round-to-nearest
    // ops (immune to contraction) to bit-match the reference's mul-then-sum.
    float d0 = 0.0f, d1 = 0.0f;
#pragma unroll
    for (int j = 0; j < 8; ++j) {
        float t0 = __fsub_rn(z[j], y0[j]);
        d0       = __fadd_rn(d0, __fmul_rn(t0, t0));
        float t1 = __fsub_rn(z[j], y1[j]);
        d1       = __fadd_rn(d1, __fmul_rn(t1, t1));
    }
    bool pick0 = d0 < d1;  // ties -> y1, matching jnp.where(d0 < d1, y0, y1)

#pragma unroll
    for (int j = 0; j < 8; ++j) q[j] = beta * (pick0 ? y0[j] : y1[j]);
}

// 1 point per thread (best measured structure). VALU-bound kernel: the
// beta==1.0 uniform fast path skips 8 IEEE divides/point (x/1.0 == x exactly).
__global__ void __launch_bounds__(256)
e8_quant_kernel(const float* __restrict__ x, const float* __restrict__ beta_p,
                const float* __restrict__ eps, float* __restrict__ out, int N) {
    int i = blockIdx.x * blockDim.x + threadIdx.x;
    if (i >= N) return;

    float beta = *beta_p;
    float e[8];
#pragma unroll
    for (int j = 0; j < 8; ++j) e[j] = eps[j];  // uniform -> scalar loads

    const f4* xp = reinterpret_cast<const f4*>(x) + (size_t)i * 2;
    f4 a = xp[0];
    f4 b = xp[1];
    float z[8] = {a.x, a.y, a.z, a.w, b.x, b.y, b.z, b.w};

    if (beta == 1.0f) {  // uniform branch; bit-exact: x/1.0 == x
#pragma unroll
        for (int j = 0; j < 8; ++j) z[j] = z[j] + e[j];
    } else {
#pragma unroll
        for (int j = 0; j < 8; ++j) z[j] = z[j] / beta + e[j];  // IEEE div
    }

    float q[8];
    e8_point(z, beta, q);

    f4* op = reinterpret_cast<f4*>(out) + (size_t)i * 2;
    f4 s0 = {q[0], q[1], q[2], q[3]};
    f4 s1 = {q[4], q[5], q[6], q[7]};
    op[0] = s0;
    op[1] = s1;
}

extern "C" void kernel_launch(void* const* d_in, const int* in_sizes, int n_in,
                              void* d_out, int out_size, void* d_ws, size_t ws_size,
                              hipStream_t stream) {
    const float* x      = (const float*)d_in[0];
    const float* beta_p = (const float*)d_in[1];
    const float* eps    = (const float*)d_in[2];
    float*       out    = (float*)d_out;

    int N     = in_sizes[0] / 8;  // 4,000,000 points
    int block = 256;
    int grid  = (N + block - 1) / block;
    hipLaunchKernelGGL(e8_quant_kernel, dim3(grid), dim3(block), 0, stream,
                       x, beta_p, eps, out, N);
}